// Round 1
// baseline (1497.538 us; speedup 1.0000x reference)
//
#include <hip/hip_runtime.h>
#include <cstdint>
#include <cstddef>

#define NN 50000
#define EE 600000
#define DD 128

__device__ __forceinline__ float leaky_f(float x){ return x > 0.f ? x : 0.01f*x; }

// ---------------- tiled f32 GEMM: C[M,Ncols] (+)= act(A[M,K] @ W[K,N] + bias) ---------
// W row-major with leading dim ldw. C leading dim ldc, column offset c0.
template<int BM,int BN,int TM,int TN,int ACT,bool ADD>
__global__ void gemm_k(const float* __restrict__ A, int M, int K,
                       const float* __restrict__ W, int ldw,
                       const float* __restrict__ bias,
                       float* __restrict__ C, int ldc, int c0)
{
    __shared__ float sA[16][BM];   // transposed A tile: sA[k][m]
    __shared__ float sW[16][BN];
    const int tid = threadIdx.x;
    const int bm = blockIdx.x * BM;
    const int bn = blockIdx.y * BN;
    constexpr int TX = BN / TN;    // threads along N
    const int tx = tid % TX;
    const int ty = tid / TX;

    float acc[TM][TN];
#pragma unroll
    for (int i=0;i<TM;i++)
#pragma unroll
        for (int j=0;j<TN;j++) acc[i][j] = 0.f;

    for (int k0 = 0; k0 < K; k0 += 16) {
        // load A tile BMx16 (float4 along K), store transposed
        {
            int row = tid >> 2;            // 0..63 (BM=64)
            int kk  = (tid & 3) << 2;      // 0,4,8,12
            int gr  = bm + row;
            float4 v = make_float4(0.f,0.f,0.f,0.f);
            if (gr < M) v = *reinterpret_cast<const float4*>(A + (size_t)gr*K + k0 + kk);
            sA[kk+0][row] = v.x; sA[kk+1][row] = v.y;
            sA[kk+2][row] = v.z; sA[kk+3][row] = v.w;
        }
        // load W tile 16xBN (float4 along N)
        {
            constexpr int CQ = BN / 4;     // float4s per row
            if (tid < 16*CQ) {
                int kr = tid / CQ;
                int cc = (tid % CQ) * 4;
                float4 v = *reinterpret_cast<const float4*>(W + (size_t)(k0+kr)*ldw + bn + cc);
                *reinterpret_cast<float4*>(&sW[kr][cc]) = v;
            }
        }
        __syncthreads();
#pragma unroll
        for (int kk=0;kk<16;kk++) {
            float a[TM], w[TN];
#pragma unroll
            for (int i=0;i<TM;i++) a[i] = sA[kk][ty*TM+i];
#pragma unroll
            for (int j=0;j<TN;j++) w[j] = sW[kk][tx*TN+j];
#pragma unroll
            for (int i=0;i<TM;i++)
#pragma unroll
                for (int j=0;j<TN;j++) acc[i][j] = fmaf(a[i], w[j], acc[i][j]);
        }
        __syncthreads();
    }

#pragma unroll
    for (int i=0;i<TM;i++) {
        int gr = bm + ty*TM + i;
        if (gr >= M) continue;
#pragma unroll
        for (int j=0;j<TN;j++) {
            int gc = bn + tx*TN + j;
            float v = acc[i][j];
            if (bias) v += bias[gc];
            float* p = C + (size_t)gr*ldc + c0 + gc;
            if (ADD) v += *p;
            if (ACT == 1) v = leaky_f(v);
            *p = v;
        }
    }
}

// ---------------- small-K projections (num: K=5 -> cols 64..95, cat: K=3 -> cols 96..127)
__global__ void numcat_k(const float* __restrict__ numf, const float* __restrict__ catf,
                         const float* __restrict__ Wn, const float* __restrict__ bn,
                         const float* __restrict__ Wc, const float* __restrict__ bc,
                         float* __restrict__ x)
{
    int t = blockIdx.x*blockDim.x + threadIdx.x;
    if (t >= NN*64) return;
    int n = t >> 6, c = t & 63;
    if (c < 32) {
        float acc = bn[c];
#pragma unroll
        for (int k=0;k<5;k++) acc = fmaf(numf[n*5+k], Wn[k*32+c], acc);
        x[(size_t)n*DD + 64 + c] = leaky_f(acc);
    } else {
        int cc = c - 32;
        float acc = bc[cc];
#pragma unroll
        for (int k=0;k<3;k++) acc = fmaf(catf[n*3+k], Wc[k*32+cc], acc);
        x[(size_t)n*DD + 96 + cc] = leaky_f(acc);
    }
}

// ---------------- ordered-uint float max encoding ----------------
// enc(f): monotone map float -> uint32.  enc(-inf) = 0x007FFFFF.
__device__ __forceinline__ unsigned enc_f(float f) {
    unsigned u = __float_as_uint(f);
    return (u & 0x80000000u) ? ~u : (u | 0x80000000u);
}
#define ENC_NEG_INF 0x007FFFFFu

__global__ void init_agg_k(unsigned* __restrict__ agg)
{
    int i = blockIdx.x*blockDim.x + threadIdx.x;   // exactly NN*DD threads
    agg[i] = ENC_NEG_INF;
}

__global__ void scatter_k(const float* __restrict__ x, const int* __restrict__ ei,
                          const int* __restrict__ et, int r, unsigned* __restrict__ agg)
{
    const long long total = (long long)EE * DD;
    long long stride = (long long)gridDim.x * blockDim.x;
    for (long long t = blockIdx.x*(long long)blockDim.x + threadIdx.x; t < total; t += stride) {
        int e = (int)(t >> 7);
        int d = (int)(t & 127);
        if (et[e] == r) {
            int s  = ei[e];        // edge_index[0][e] = src
            int dn = ei[EE + e];   // edge_index[1][e] = dst
            unsigned v = enc_f(x[(size_t)s*DD + d]);
            atomicMax(&agg[(size_t)dn*DD + d], v);
        }
    }
}

__global__ void decode_k(unsigned* __restrict__ agg)
{
    int i = blockIdx.x*blockDim.x + threadIdx.x;   // exactly NN*DD threads
    unsigned e = agg[i];
    float f;
    if (e == ENC_NEG_INF) f = 0.f;                         // empty segment -> 0
    else if (e & 0x80000000u) f = __uint_as_float(e ^ 0x80000000u);
    else f = __uint_as_float(~e);
    reinterpret_cast<float*>(agg)[i] = f;
}

// ---------------- graph layernorm ----------------
__global__ void zero_k(float* __restrict__ red)
{
    if (threadIdx.x < 4) red[threadIdx.x] = 0.f;
}

__global__ void reduce_k(const float* __restrict__ x, float* __restrict__ red)
{
    const int total = NN*DD;
    float s = 0.f, ss = 0.f;
    for (int i = blockIdx.x*blockDim.x + threadIdx.x; i < total; i += gridDim.x*blockDim.x) {
        float v = x[i];
        s += v; ss = fmaf(v, v, ss);
    }
#pragma unroll
    for (int o=32;o>0;o>>=1) { s += __shfl_down(s,o); ss += __shfl_down(ss,o); }
    __shared__ float bs[4], bss[4];
    int wid = threadIdx.x >> 6, lane = threadIdx.x & 63;
    if (lane == 0) { bs[wid] = s; bss[wid] = ss; }
    __syncthreads();
    if (threadIdx.x == 0) {
        float S = bs[0]+bs[1]+bs[2]+bs[3];
        float SS = bss[0]+bss[1]+bss[2]+bss[3];
        atomicAdd(&red[0], S);
        atomicAdd(&red[1], SS);
    }
}

__global__ void norm_k(float* __restrict__ x, const float* __restrict__ g,
                       const float* __restrict__ b, const float* __restrict__ red)
{
    const float inv = 1.f / (float)(NN*DD);
    float mu  = red[0] * inv;
    float var = red[1] * inv - mu*mu;
    float rstd = rsqrtf(var + 1e-5f);
    int i = blockIdx.x*blockDim.x + threadIdx.x;   // exactly NN*DD threads
    int c = i & 127;
    x[i] = (x[i]-mu)*rstd*g[c] + b[c];
}

// ---------------- head: out[n] = sigmoid(h . W3 + b3), h precomputed = leaky(x@W2+b2)
__global__ void head_k(const float* __restrict__ h, const float* __restrict__ W3,
                       const float* __restrict__ b3, float* __restrict__ out)
{
    int n = blockIdx.x;
    int t = threadIdx.x;    // 128
    float p = h[(size_t)n*DD + t] * W3[t];
#pragma unroll
    for (int o=32;o>0;o>>=1) p += __shfl_down(p,o);
    __shared__ float s2[2];
    if ((t & 63) == 0) s2[t>>6] = p;
    __syncthreads();
    if (t == 0) {
        float l = s2[0] + s2[1] + b3[0];
        out[n] = 1.f / (1.f + expf(-l));
    }
}

extern "C" void kernel_launch(void* const* d_in, const int* in_sizes, int n_in,
                              void* d_out, int out_size, void* d_ws, size_t ws_size,
                              hipStream_t stream)
{
    const float* desc  = (const float*)d_in[0];
    const float* tweet = (const float*)d_in[1];
    const float* numf  = (const float*)d_in[2];
    const float* catf  = (const float*)d_in[3];
    const int*   ei    = (const int*)d_in[4];
    const int*   et    = (const int*)d_in[5];
    const float* Wd=(const float*)d_in[6];  const float* bd=(const float*)d_in[7];
    const float* Wt=(const float*)d_in[8];  const float* bt=(const float*)d_in[9];
    const float* Wn=(const float*)d_in[10]; const float* bn=(const float*)d_in[11];
    const float* Wc=(const float*)d_in[12]; const float* bc=(const float*)d_in[13];
    const float* W1=(const float*)d_in[14]; const float* b1=(const float*)d_in[15];
    const float* rg1w=(const float*)d_in[16]; const float* rg1root=(const float*)d_in[17];
    const float* rg1b=(const float*)d_in[18];
    const float* ln1g=(const float*)d_in[19]; const float* ln1b=(const float*)d_in[20];
    const float* rg2w=(const float*)d_in[21]; const float* rg2root=(const float*)d_in[22];
    const float* rg2b=(const float*)d_in[23];
    const float* ln2g=(const float*)d_in[24]; const float* ln2b=(const float*)d_in[25];
    const float* W2=(const float*)d_in[26]; const float* b2=(const float*)d_in[27];
    const float* W3=(const float*)d_in[28]; const float* b3=(const float*)d_in[29];
    float* out = (float*)d_out;

    // workspace: xa, xb, agg (each NN*DD f32) + red (4 f32)  => ~77 MB
    float* xa  = (float*)d_ws;
    float* xb  = xa + (size_t)NN*DD;
    float* agg = xb + (size_t)NN*DD;
    float* red = agg + (size_t)NN*DD;

    dim3 blk(256);
    dim3 gproj((NN+63)/64, 1);
    dim3 g128((NN+63)/64, 2);
    const int nelm_blocks = (NN*DD)/256;   // 25000, exact

    // x = concat(leaky(desc@Wd+bd), leaky(tweet@Wt+bt), leaky(num@Wn+bn), leaky(cat@Wc+bc))
    hipLaunchKernelGGL((gemm_k<64,32,4,2,1,false>), gproj, blk, 0, stream,
                       desc, NN, 768, Wd, 32, bd, xa, DD, 0);
    hipLaunchKernelGGL((gemm_k<64,32,4,2,1,false>), gproj, blk, 0, stream,
                       tweet, NN, 768, Wt, 32, bt, xa, DD, 32);
    numcat_k<<<(NN*64)/256, 256, 0, stream>>>(numf, catf, Wn, bn, Wc, bc, xa);

    // x = leaky(x@W1 + b1) -> xb
    hipLaunchKernelGGL((gemm_k<64,64,4,4,1,false>), g128, blk, 0, stream,
                       xa, NN, 128, W1, 128, b1, xb, DD, 0);

    // ---- RGCN layer 1: xa = xb@root + bias + sum_r maxagg_r(xb) @ W_r
    hipLaunchKernelGGL((gemm_k<64,64,4,4,0,false>), g128, blk, 0, stream,
                       xb, NN, 128, rg1root, 128, rg1b, xa, DD, 0);
    for (int r=0;r<2;r++) {
        init_agg_k<<<nelm_blocks, 256, 0, stream>>>((unsigned*)agg);
        scatter_k<<<8192, 256, 0, stream>>>(xb, ei, et, r, (unsigned*)agg);
        decode_k<<<nelm_blocks, 256, 0, stream>>>((unsigned*)agg);
        hipLaunchKernelGGL((gemm_k<64,64,4,4,0,true>), g128, blk, 0, stream,
                           agg, NN, 128, rg1w + (size_t)r*DD*DD, 128, nullptr, xa, DD, 0);
    }
    zero_k<<<1, 64, 0, stream>>>(red);
    reduce_k<<<512, 256, 0, stream>>>(xa, red);
    norm_k<<<nelm_blocks, 256, 0, stream>>>(xa, ln1g, ln1b, red);

    // ---- RGCN layer 2: xb = xa@root + bias + sum_r maxagg_r(xa) @ W_r
    hipLaunchKernelGGL((gemm_k<64,64,4,4,0,false>), g128, blk, 0, stream,
                       xa, NN, 128, rg2root, 128, rg2b, xb, DD, 0);
    for (int r=0;r<2;r++) {
        init_agg_k<<<nelm_blocks, 256, 0, stream>>>((unsigned*)agg);
        scatter_k<<<8192, 256, 0, stream>>>(xa, ei, et, r, (unsigned*)agg);
        decode_k<<<nelm_blocks, 256, 0, stream>>>((unsigned*)agg);
        hipLaunchKernelGGL((gemm_k<64,64,4,4,0,true>), g128, blk, 0, stream,
                           agg, NN, 128, rg2w + (size_t)r*DD*DD, 128, nullptr, xb, DD, 0);
    }
    zero_k<<<1, 64, 0, stream>>>(red);
    reduce_k<<<512, 256, 0, stream>>>(xb, red);
    norm_k<<<nelm_blocks, 256, 0, stream>>>(xb, ln2g, ln2b, red);

    // head: xa = leaky(xb@W2+b2); out = sigmoid(xa@W3 + b3)
    hipLaunchKernelGGL((gemm_k<64,64,4,4,1,false>), g128, blk, 0, stream,
                       xb, NN, 128, W2, 128, b2, xa, DD, 0);
    head_k<<<NN, 128, 0, stream>>>(xa, W3, b3, out);
}

// Round 2
// 1303.914 us; speedup vs baseline: 1.1485x; 1.1485x over previous
//
#include <hip/hip_runtime.h>
#include <cstdint>
#include <cstddef>

#define NN 50000
#define EE 600000
#define DD 128
#define NSEG (NN*2)

__device__ __forceinline__ float leaky_f(float x){ return x > 0.f ? x : 0.01f*x; }

// ---------------- tiled f32 GEMM: C[M,N] (+)= act(A[M,K] @ W[K,N] + bias) ----------
// BM=128 fixed. 256 threads. TM=8. W row-major ldw; C leading dim ldc, col offset c0.
template<int BM,int BN,int TM,int TN,int ACT,bool ADD>
__global__ __launch_bounds__(256) void gemm_k(
                       const float* __restrict__ A, int M, int K,
                       const float* __restrict__ W, int ldw,
                       const float* __restrict__ bias,
                       float* __restrict__ C, int ldc, int c0)
{
    static_assert(BM == 128 && TM == 8, "layout assumes BM=128, TM=8");
    __shared__ float sA[16][BM];   // transposed A tile: sA[k][m]
    __shared__ float sW[16][BN];
    const int tid = threadIdx.x;
    const int bm = blockIdx.x * BM;
    const int bn = blockIdx.y * BN;
    constexpr int TX = BN / TN;    // threads along N (16)
    const int tx = tid % TX;
    const int ty = tid / TX;       // 0..15

    float acc[TM][TN];
#pragma unroll
    for (int i=0;i<TM;i++)
#pragma unroll
        for (int j=0;j<TN;j++) acc[i][j] = 0.f;

    for (int k0 = 0; k0 < K; k0 += 16) {
        // A tile: 128 rows x 16 k. Each thread: 2 float4 along K for one row.
        {
            int row = tid >> 1;            // 0..127
            int kk  = (tid & 1) << 3;      // 0 or 8
            int gr  = bm + row;
            float4 v0 = make_float4(0.f,0.f,0.f,0.f);
            float4 v1 = v0;
            if (gr < M) {
                const float* p = A + (size_t)gr*K + k0 + kk;
                v0 = *reinterpret_cast<const float4*>(p);
                v1 = *reinterpret_cast<const float4*>(p+4);
            }
            sA[kk+0][row] = v0.x; sA[kk+1][row] = v0.y;
            sA[kk+2][row] = v0.z; sA[kk+3][row] = v0.w;
            sA[kk+4][row] = v1.x; sA[kk+5][row] = v1.y;
            sA[kk+6][row] = v1.z; sA[kk+7][row] = v1.w;
        }
        // W tile: 16 rows x BN cols
        {
            constexpr int CQ = BN / 4;     // float4s per row
            if (tid < 16*CQ) {
                int kr = tid / CQ;
                int cc = (tid % CQ) * 4;
                float4 v = *reinterpret_cast<const float4*>(W + (size_t)(k0+kr)*ldw + bn + cc);
                *reinterpret_cast<float4*>(&sW[kr][cc]) = v;
            }
        }
        __syncthreads();
#pragma unroll
        for (int kk=0;kk<16;kk++) {
            float a[TM], w[TN];
#pragma unroll
            for (int i=0;i<TM;i+=4)
                *reinterpret_cast<float4*>(&a[i]) =
                    *reinterpret_cast<const float4*>(&sA[kk][ty*TM+i]);
#pragma unroll
            for (int j=0;j<TN;j+=2)
                *reinterpret_cast<float2*>(&w[j]) =
                    *reinterpret_cast<const float2*>(&sW[kk][tx*TN+j]);
#pragma unroll
            for (int i=0;i<TM;i++)
#pragma unroll
                for (int j=0;j<TN;j++) acc[i][j] = fmaf(a[i], w[j], acc[i][j]);
        }
        __syncthreads();
    }

#pragma unroll
    for (int i=0;i<TM;i++) {
        int gr = bm + ty*TM + i;
        if (gr >= M) continue;
#pragma unroll
        for (int j=0;j<TN;j++) {
            int gc = bn + tx*TN + j;
            float v = acc[i][j];
            if (bias) v += bias[gc];
            float* p = C + (size_t)gr*ldc + c0 + gc;
            if (ADD) v += *p;
            if (ACT == 1) v = leaky_f(v);
            *p = v;
        }
    }
}

// ---------------- small-K projections (num: K=5 -> cols 64..95, cat: K=3 -> cols 96..127)
__global__ void numcat_k(const float* __restrict__ numf, const float* __restrict__ catf,
                         const float* __restrict__ Wn, const float* __restrict__ bn,
                         const float* __restrict__ Wc, const float* __restrict__ bc,
                         float* __restrict__ x)
{
    int t = blockIdx.x*blockDim.x + threadIdx.x;
    if (t >= NN*64) return;
    int n = t >> 6, c = t & 63;
    if (c < 32) {
        float acc = bn[c];
#pragma unroll
        for (int k=0;k<5;k++) acc = fmaf(numf[n*5+k], Wn[k*32+c], acc);
        x[(size_t)n*DD + 64 + c] = leaky_f(acc);
    } else {
        int cc = c - 32;
        float acc = bc[cc];
#pragma unroll
        for (int k=0;k<3;k++) acc = fmaf(catf[n*3+k], Wc[k*32+cc], acc);
        x[(size_t)n*DD + 96 + cc] = leaky_f(acc);
    }
}

// ---------------- CSR build (once per call; shared by both RGCN layers) ----------------
__global__ void zero_int_k(int* __restrict__ p, int n)
{
    int i = blockIdx.x*blockDim.x + threadIdx.x;
    if (i < n) p[i] = 0;
}

__global__ void hist_k(const int* __restrict__ ei, const int* __restrict__ et,
                       int* __restrict__ deg)
{
    int e = blockIdx.x*blockDim.x + threadIdx.x;
    if (e >= EE) return;
    atomicAdd(&deg[ei[EE + e]*2 + et[e]], 1);
}

// single-block exclusive scan over NSEG entries -> offs[0..NSEG], cursor copy
__global__ __launch_bounds__(1024) void scan_k(const int* __restrict__ deg,
                                               int* __restrict__ offs,
                                               int* __restrict__ cursor)
{
    const int CH = (NSEG + 1023) / 1024;   // 98
    int t = threadIdx.x;
    int beg = t*CH, end = min(beg + CH, NSEG);
    int s = 0;
    for (int i=beg;i<end;i++) s += deg[i];
    __shared__ int ps[1024];
    ps[t] = s; __syncthreads();
    for (int o=1;o<1024;o<<=1) {
        int v = (t >= o) ? ps[t-o] : 0;
        __syncthreads();
        ps[t] += v;
        __syncthreads();
    }
    int run = (t == 0) ? 0 : ps[t-1];
    for (int i=beg;i<end;i++) {
        int d = deg[i];
        offs[i] = run; cursor[i] = run;
        run += d;
    }
    if (t == 1023) offs[NSEG] = run;   // == EE
}

__global__ void place_k(const int* __restrict__ ei, const int* __restrict__ et,
                        int* __restrict__ cursor, unsigned short* __restrict__ csr)
{
    int e = blockIdx.x*blockDim.x + threadIdx.x;
    if (e >= EE) return;
    int r = et[e], dst = ei[EE + e], src = ei[e];
    int pos = atomicAdd(&cursor[dst*2 + r], 1);
    csr[pos] = (unsigned short)src;    // N=50000 < 65536
}

// ---------------- max-gather per (node, rel): one wave per node ----------------
__global__ void gather_k(const float* __restrict__ x, const int* __restrict__ offs,
                         const unsigned short* __restrict__ csr, int r,
                         float* __restrict__ agg)
{
    int gw = (blockIdx.x*blockDim.x + threadIdx.x) >> 6;  // global wave = node
    int lane = threadIdx.x & 63;
    if (gw >= NN) return;
    int seg = gw*2 + r;
    int beg = offs[seg], end = offs[seg+1];
    float2 m = make_float2(-3.402823466e+38f, -3.402823466e+38f);
    for (int j=beg;j<end;j++) {
        int src = csr[j];
        float2 v = *reinterpret_cast<const float2*>(x + (size_t)src*DD + lane*2);
        m.x = fmaxf(m.x, v.x);
        m.y = fmaxf(m.y, v.y);
    }
    if (beg == end) { m.x = 0.f; m.y = 0.f; }   // empty segment -> 0 (isinf replace)
    *reinterpret_cast<float2*>(agg + (size_t)gw*DD + lane*2) = m;
}

// ---------------- graph layernorm ----------------
__global__ void zero_red_k(float* __restrict__ red)
{
    if (threadIdx.x < 4) red[threadIdx.x] = 0.f;
}

__global__ void reduce_k(const float* __restrict__ x, float* __restrict__ red)
{
    const int total = NN*DD;
    float s = 0.f, ss = 0.f;
    for (int i = blockIdx.x*blockDim.x + threadIdx.x; i < total; i += gridDim.x*blockDim.x) {
        float v = x[i];
        s += v; ss = fmaf(v, v, ss);
    }
#pragma unroll
    for (int o=32;o>0;o>>=1) { s += __shfl_down(s,o); ss += __shfl_down(ss,o); }
    __shared__ float bs[4], bss[4];
    int wid = threadIdx.x >> 6, lane = threadIdx.x & 63;
    if (lane == 0) { bs[wid] = s; bss[wid] = ss; }
    __syncthreads();
    if (threadIdx.x == 0) {
        atomicAdd(&red[0], bs[0]+bs[1]+bs[2]+bs[3]);
        atomicAdd(&red[1], bss[0]+bss[1]+bss[2]+bss[3]);
    }
}

__global__ void norm_k(float* __restrict__ x, const float* __restrict__ g,
                       const float* __restrict__ b, const float* __restrict__ red)
{
    const float inv = 1.f / (float)(NN*DD);
    float mu  = red[0] * inv;
    float var = red[1] * inv - mu*mu;
    float rstd = rsqrtf(var + 1e-5f);
    int i = blockIdx.x*blockDim.x + threadIdx.x;   // exactly NN*DD threads
    int c = i & 127;
    x[i] = (x[i]-mu)*rstd*g[c] + b[c];
}

// ---------------- head: out[n] = sigmoid(h . W3 + b3) ----------------
__global__ void head_k(const float* __restrict__ h, const float* __restrict__ W3,
                       const float* __restrict__ b3, float* __restrict__ out)
{
    int n = blockIdx.x;
    int t = threadIdx.x;    // 128
    float p = h[(size_t)n*DD + t] * W3[t];
#pragma unroll
    for (int o=32;o>0;o>>=1) p += __shfl_down(p,o);
    __shared__ float s2[2];
    if ((t & 63) == 0) s2[t>>6] = p;
    __syncthreads();
    if (t == 0) {
        float l = s2[0] + s2[1] + b3[0];
        out[n] = 1.f / (1.f + expf(-l));
    }
}

extern "C" void kernel_launch(void* const* d_in, const int* in_sizes, int n_in,
                              void* d_out, int out_size, void* d_ws, size_t ws_size,
                              hipStream_t stream)
{
    const float* desc  = (const float*)d_in[0];
    const float* tweet = (const float*)d_in[1];
    const float* numf  = (const float*)d_in[2];
    const float* catf  = (const float*)d_in[3];
    const int*   ei    = (const int*)d_in[4];
    const int*   et    = (const int*)d_in[5];
    const float* Wd=(const float*)d_in[6];  const float* bd=(const float*)d_in[7];
    const float* Wt=(const float*)d_in[8];  const float* bt=(const float*)d_in[9];
    const float* Wn=(const float*)d_in[10]; const float* bn=(const float*)d_in[11];
    const float* Wc=(const float*)d_in[12]; const float* bc=(const float*)d_in[13];
    const float* W1=(const float*)d_in[14]; const float* b1=(const float*)d_in[15];
    const float* rg1w=(const float*)d_in[16]; const float* rg1root=(const float*)d_in[17];
    const float* rg1b=(const float*)d_in[18];
    const float* ln1g=(const float*)d_in[19]; const float* ln1b=(const float*)d_in[20];
    const float* rg2w=(const float*)d_in[21]; const float* rg2root=(const float*)d_in[22];
    const float* rg2b=(const float*)d_in[23];
    const float* ln2g=(const float*)d_in[24]; const float* ln2b=(const float*)d_in[25];
    const float* W2=(const float*)d_in[26]; const float* b2=(const float*)d_in[27];
    const float* W3=(const float*)d_in[28]; const float* b3=(const float*)d_in[29];
    float* out = (float*)d_out;

    // workspace layout (~79.2 MB)
    float* xa  = (float*)d_ws;                       // NN*DD
    float* xb  = xa + (size_t)NN*DD;                 // NN*DD
    float* agg = xb + (size_t)NN*DD;                 // NN*DD
    float* red = agg + (size_t)NN*DD;                // 4
    int*   deg    = (int*)(red + 4);                 // NSEG
    int*   offs   = deg + NSEG;                      // NSEG+1
    int*   cursor = offs + NSEG + 1;                 // NSEG
    unsigned short* csr = (unsigned short*)(cursor + NSEG);  // EE u16

    dim3 blk(256);
    dim3 gA((NN+127)/128, 2);     // main GEMMs (BN=64, 128 cols)
    dim3 gP((NN+127)/128, 1);     // projections (BN=32)
    const int nelm_blocks = (NN*DD)/256;     // 25000, exact
    const int edge_blocks = (EE+255)/256;    // 2344
    const int gat_blocks  = (NN*64+255)/256; // 12500

    // ---- feature projections -> xa
    hipLaunchKernelGGL((gemm_k<128,32,8,2,1,false>), gP, blk, 0, stream,
                       desc, NN, 768, Wd, 32, bd, xa, DD, 0);
    hipLaunchKernelGGL((gemm_k<128,32,8,2,1,false>), gP, blk, 0, stream,
                       tweet, NN, 768, Wt, 32, bt, xa, DD, 32);
    numcat_k<<<(NN*64)/256, 256, 0, stream>>>(numf, catf, Wn, bn, Wc, bc, xa);

    // ---- CSR build (edges identical for both layers; build once)
    zero_int_k<<<(NSEG+255)/256, 256, 0, stream>>>(deg, NSEG);
    hist_k<<<edge_blocks, 256, 0, stream>>>(ei, et, deg);
    scan_k<<<1, 1024, 0, stream>>>(deg, offs, cursor);
    place_k<<<edge_blocks, 256, 0, stream>>>(ei, et, cursor, csr);

    // ---- x = leaky(x@W1 + b1) -> xb
    hipLaunchKernelGGL((gemm_k<128,64,8,4,1,false>), gA, blk, 0, stream,
                       xa, NN, 128, W1, 128, b1, xb, DD, 0);

    // ---- RGCN layer 1: xa = xb@root + bias + sum_r maxagg_r(xb) @ W_r
    hipLaunchKernelGGL((gemm_k<128,64,8,4,0,false>), gA, blk, 0, stream,
                       xb, NN, 128, rg1root, 128, rg1b, xa, DD, 0);
    for (int r=0;r<2;r++) {
        gather_k<<<gat_blocks, 256, 0, stream>>>(xb, offs, csr, r, agg);
        hipLaunchKernelGGL((gemm_k<128,64,8,4,0,true>), gA, blk, 0, stream,
                           agg, NN, 128, rg1w + (size_t)r*DD*DD, 128, nullptr, xa, DD, 0);
    }
    zero_red_k<<<1, 64, 0, stream>>>(red);
    reduce_k<<<512, 256, 0, stream>>>(xa, red);
    norm_k<<<nelm_blocks, 256, 0, stream>>>(xa, ln1g, ln1b, red);

    // ---- RGCN layer 2: xb = xa@root + bias + sum_r maxagg_r(xa) @ W_r
    hipLaunchKernelGGL((gemm_k<128,64,8,4,0,false>), gA, blk, 0, stream,
                       xa, NN, 128, rg2root, 128, rg2b, xb, DD, 0);
    for (int r=0;r<2;r++) {
        gather_k<<<gat_blocks, 256, 0, stream>>>(xa, offs, csr, r, agg);
        hipLaunchKernelGGL((gemm_k<128,64,8,4,0,true>), gA, blk, 0, stream,
                           agg, NN, 128, rg2w + (size_t)r*DD*DD, 128, nullptr, xb, DD, 0);
    }
    zero_red_k<<<1, 64, 0, stream>>>(red);
    reduce_k<<<512, 256, 0, stream>>>(xb, red);
    norm_k<<<nelm_blocks, 256, 0, stream>>>(xb, ln2g, ln2b, red);

    // ---- head: xa = leaky(xb@W2+b2); out = sigmoid(xa@W3 + b3)
    hipLaunchKernelGGL((gemm_k<128,64,8,4,1,false>), gA, blk, 0, stream,
                       xb, NN, 128, W2, 128, b2, xa, DD, 0);
    head_k<<<NN, 128, 0, stream>>>(xa, W3, b3, out);
}

// Round 3
// 1219.948 us; speedup vs baseline: 1.2275x; 1.0688x over previous
//
#include <hip/hip_runtime.h>
#include <cstdint>
#include <cstddef>

#define NN 50000
#define EE 600000
#define DD 128
#define NSEG (NN*2)
#define NPART ((NSEG + 255) / 256)   // 391

__device__ __forceinline__ float leaky_f(float x){ return x > 0.f ? x : 0.01f*x; }

// ---------------- tiled f32 GEMM: C[M,N] (+)= act(A[M,K] @ W[K,N] + bias) ----------
// BM=128 fixed, 256 threads, TM=8. W row-major ldw; C leading dim ldc, col offset c0.
template<int BM,int BN,int TM,int TN,int ACT,bool ADD>
__global__ __launch_bounds__(256) void gemm_k(
                       const float* __restrict__ A, int M, int K,
                       const float* __restrict__ W, int ldw,
                       const float* __restrict__ bias,
                       float* __restrict__ C, int ldc, int c0)
{
    static_assert(BM == 128 && TM == 8, "layout assumes BM=128, TM=8");
    __shared__ float sA[16][BM];   // transposed A tile: sA[k][m]
    __shared__ float sW[16][BN];
    const int tid = threadIdx.x;
    const int bm = blockIdx.x * BM;
    const int bn = blockIdx.y * BN;
    constexpr int TX = BN / TN;    // threads along N
    const int tx = tid % TX;
    const int ty = tid / TX;

    float acc[TM][TN];
#pragma unroll
    for (int i=0;i<TM;i++)
#pragma unroll
        for (int j=0;j<TN;j++) acc[i][j] = 0.f;

    for (int k0 = 0; k0 < K; k0 += 16) {
        // A tile: 128 rows x 16 k. Each thread: 2 float4 along K for one row.
        {
            int row = tid >> 1;            // 0..127
            int kk  = (tid & 1) << 3;      // 0 or 8
            int gr  = bm + row;
            float4 v0 = make_float4(0.f,0.f,0.f,0.f);
            float4 v1 = v0;
            if (gr < M) {
                const float* p = A + (size_t)gr*K + k0 + kk;
                v0 = *reinterpret_cast<const float4*>(p);
                v1 = *reinterpret_cast<const float4*>(p+4);
            }
            sA[kk+0][row] = v0.x; sA[kk+1][row] = v0.y;
            sA[kk+2][row] = v0.z; sA[kk+3][row] = v0.w;
            sA[kk+4][row] = v1.x; sA[kk+5][row] = v1.y;
            sA[kk+6][row] = v1.z; sA[kk+7][row] = v1.w;
        }
        // W tile: 16 rows x BN cols (loop in case 16*CQ > 256)
        {
            constexpr int CQ = BN / 4;     // float4s per row
#pragma unroll
            for (int idx = tid; idx < 16*CQ; idx += 256) {
                int kr = idx / CQ;
                int cc = (idx % CQ) * 4;
                float4 v = *reinterpret_cast<const float4*>(W + (size_t)(k0+kr)*ldw + bn + cc);
                *reinterpret_cast<float4*>(&sW[kr][cc]) = v;
            }
        }
        __syncthreads();
#pragma unroll
        for (int kk=0;kk<16;kk++) {
            float a[TM], w[TN];
#pragma unroll
            for (int i=0;i<TM;i+=4)
                *reinterpret_cast<float4*>(&a[i]) =
                    *reinterpret_cast<const float4*>(&sA[kk][ty*TM+i]);
            if constexpr (TN % 4 == 0) {
#pragma unroll
                for (int j=0;j<TN;j+=4)
                    *reinterpret_cast<float4*>(&w[j]) =
                        *reinterpret_cast<const float4*>(&sW[kk][tx*TN+j]);
            } else {
#pragma unroll
                for (int j=0;j<TN;j+=2)
                    *reinterpret_cast<float2*>(&w[j]) =
                        *reinterpret_cast<const float2*>(&sW[kk][tx*TN+j]);
            }
#pragma unroll
            for (int i=0;i<TM;i++)
#pragma unroll
                for (int j=0;j<TN;j++) acc[i][j] = fmaf(a[i], w[j], acc[i][j]);
        }
        __syncthreads();
    }

#pragma unroll
    for (int i=0;i<TM;i++) {
        int gr = bm + ty*TM + i;
        if (gr >= M) continue;
#pragma unroll
        for (int j=0;j<TN;j++) {
            int gc = bn + tx*TN + j;
            float v = acc[i][j];
            if (bias) v += bias[gc];
            float* p = C + (size_t)gr*ldc + c0 + gc;
            if (ADD) v += *p;
            if (ACT == 1) v = leaky_f(v);
            *p = v;
        }
    }
}

// ---------------- small-K projections (num: K=5 -> cols 64..95, cat: K=3 -> cols 96..127)
__global__ void numcat_k(const float* __restrict__ numf, const float* __restrict__ catf,
                         const float* __restrict__ Wn, const float* __restrict__ bn,
                         const float* __restrict__ Wc, const float* __restrict__ bc,
                         float* __restrict__ x)
{
    int t = blockIdx.x*blockDim.x + threadIdx.x;
    if (t >= NN*64) return;
    int n = t >> 6, c = t & 63;
    if (c < 32) {
        float acc = bn[c];
#pragma unroll
        for (int k=0;k<5;k++) acc = fmaf(numf[n*5+k], Wn[k*32+c], acc);
        x[(size_t)n*DD + 64 + c] = leaky_f(acc);
    } else {
        int cc = c - 32;
        float acc = bc[cc];
#pragma unroll
        for (int k=0;k<3;k++) acc = fmaf(catf[n*3+k], Wc[k*32+cc], acc);
        x[(size_t)n*DD + 96 + cc] = leaky_f(acc);
    }
}

// ---------------- CSR build (once per call; shared by both RGCN layers) ----------------
__global__ void zero_int_k(int* __restrict__ p, int n)
{
    int i = blockIdx.x*blockDim.x + threadIdx.x;
    if (i < n) p[i] = 0;
}

__global__ void hist_k(const int* __restrict__ ei, const int* __restrict__ et,
                       int* __restrict__ deg)
{
    int e = blockIdx.x*blockDim.x + threadIdx.x;
    if (e >= EE) return;
    atomicAdd(&deg[ei[EE + e]*2 + et[e]], 1);
}

// hierarchical scan: (1) per-block sums, (2) scan partials, (3) per-block scan+write
__global__ __launch_bounds__(256) void part_reduce_k(const int* __restrict__ deg,
                                                     int* __restrict__ part)
{
    __shared__ int s[256];
    int t = threadIdx.x;
    int i = blockIdx.x*256 + t;
    s[t] = (i < NSEG) ? deg[i] : 0;
    __syncthreads();
#pragma unroll
    for (int o=128;o>0;o>>=1) {
        if (t < o) s[t] += s[t+o];
        __syncthreads();
    }
    if (t == 0) part[blockIdx.x] = s[0];
}

__global__ __launch_bounds__(512) void part_scan_k(int* __restrict__ part)
{
    __shared__ int ps[512];
    int t = threadIdx.x;
    int v = (t < NPART) ? part[t] : 0;
    ps[t] = v; __syncthreads();
    for (int o=1;o<512;o<<=1) {
        int u = (t >= o) ? ps[t-o] : 0;
        __syncthreads();
        ps[t] += u;
        __syncthreads();
    }
    if (t < NPART) part[t] = ps[t] - v;   // exclusive
}

__global__ __launch_bounds__(256) void final_scan_k(const int* __restrict__ deg,
                                                    const int* __restrict__ part,
                                                    int* __restrict__ offs,
                                                    int* __restrict__ cursor)
{
    __shared__ int ps[256];
    int t = threadIdx.x;
    int i = blockIdx.x*256 + t;
    int d = (i < NSEG) ? deg[i] : 0;
    ps[t] = d; __syncthreads();
    for (int o=1;o<256;o<<=1) {
        int u = (t >= o) ? ps[t-o] : 0;
        __syncthreads();
        ps[t] += u;
        __syncthreads();
    }
    if (i < NSEG) {
        int off = part[blockIdx.x] + ps[t] - d;
        offs[i] = off; cursor[i] = off;
    }
    if (blockIdx.x == 0 && t == 0) offs[NSEG] = EE;
}

__global__ void place_k(const int* __restrict__ ei, const int* __restrict__ et,
                        int* __restrict__ cursor, unsigned short* __restrict__ csr)
{
    int e = blockIdx.x*blockDim.x + threadIdx.x;
    if (e >= EE) return;
    int r = et[e], dst = ei[EE + e], src = ei[e];
    int pos = atomicAdd(&cursor[dst*2 + r], 1);
    csr[pos] = (unsigned short)src;    // N=50000 < 65536
}

// ---------------- max-gather per (node, rel): one wave per node ----------------
__global__ void gather_k(const float* __restrict__ x, const int* __restrict__ offs,
                         const unsigned short* __restrict__ csr, int r,
                         float* __restrict__ agg)
{
    int gw = (blockIdx.x*blockDim.x + threadIdx.x) >> 6;  // global wave = node
    int lane = threadIdx.x & 63;
    if (gw >= NN) return;
    int seg = gw*2 + r;
    int beg = offs[seg], end = offs[seg+1];
    float2 m = make_float2(-3.402823466e+38f, -3.402823466e+38f);
    for (int j=beg;j<end;j++) {
        int src = csr[j];
        float2 v = *reinterpret_cast<const float2*>(x + (size_t)src*DD + lane*2);
        m.x = fmaxf(m.x, v.x);
        m.y = fmaxf(m.y, v.y);
    }
    if (beg == end) { m.x = 0.f; m.y = 0.f; }   // empty segment -> 0
    *reinterpret_cast<float2*>(agg + (size_t)gw*DD + lane*2) = m;
}

// ---------------- graph layernorm ----------------
__global__ void zero_red_k(float* __restrict__ red)
{
    if (threadIdx.x < 4) red[threadIdx.x] = 0.f;
}

__global__ void reduce_k(const float* __restrict__ x, float* __restrict__ red)
{
    const int total = NN*DD;
    float s = 0.f, ss = 0.f;
    for (int i = blockIdx.x*blockDim.x + threadIdx.x; i < total; i += gridDim.x*blockDim.x) {
        float v = x[i];
        s += v; ss = fmaf(v, v, ss);
    }
#pragma unroll
    for (int o=32;o>0;o>>=1) { s += __shfl_down(s,o); ss += __shfl_down(ss,o); }
    __shared__ float bs[4], bss[4];
    int wid = threadIdx.x >> 6, lane = threadIdx.x & 63;
    if (lane == 0) { bs[wid] = s; bss[wid] = ss; }
    __syncthreads();
    if (threadIdx.x == 0) {
        atomicAdd(&red[0], bs[0]+bs[1]+bs[2]+bs[3]);
        atomicAdd(&red[1], bss[0]+bss[1]+bss[2]+bss[3]);
    }
}

__global__ void norm_k(float* __restrict__ x, const float* __restrict__ g,
                       const float* __restrict__ b, const float* __restrict__ red)
{
    const float inv = 1.f / (float)(NN*DD);
    float mu  = red[0] * inv;
    float var = red[1] * inv - mu*mu;
    float rstd = rsqrtf(var + 1e-5f);
    int i = blockIdx.x*blockDim.x + threadIdx.x;   // exactly NN*DD threads
    int c = i & 127;
    x[i] = (x[i]-mu)*rstd*g[c] + b[c];
}

// ---------------- head: out[n] = sigmoid(h . W3 + b3) ----------------
__global__ void head_k(const float* __restrict__ h, const float* __restrict__ W3,
                       const float* __restrict__ b3, float* __restrict__ out)
{
    int n = blockIdx.x;
    int t = threadIdx.x;    // 128
    float p = h[(size_t)n*DD + t] * W3[t];
#pragma unroll
    for (int o=32;o>0;o>>=1) p += __shfl_down(p,o);
    __shared__ float s2[2];
    if ((t & 63) == 0) s2[t>>6] = p;
    __syncthreads();
    if (t == 0) {
        float l = s2[0] + s2[1] + b3[0];
        out[n] = 1.f / (1.f + expf(-l));
    }
}

extern "C" void kernel_launch(void* const* d_in, const int* in_sizes, int n_in,
                              void* d_out, int out_size, void* d_ws, size_t ws_size,
                              hipStream_t stream)
{
    const float* desc  = (const float*)d_in[0];
    const float* tweet = (const float*)d_in[1];
    const float* numf  = (const float*)d_in[2];
    const float* catf  = (const float*)d_in[3];
    const int*   ei    = (const int*)d_in[4];
    const int*   et    = (const int*)d_in[5];
    const float* Wd=(const float*)d_in[6];  const float* bd=(const float*)d_in[7];
    const float* Wt=(const float*)d_in[8];  const float* bt=(const float*)d_in[9];
    const float* Wn=(const float*)d_in[10]; const float* bn=(const float*)d_in[11];
    const float* Wc=(const float*)d_in[12]; const float* bc=(const float*)d_in[13];
    const float* W1=(const float*)d_in[14]; const float* b1=(const float*)d_in[15];
    const float* rg1w=(const float*)d_in[16]; const float* rg1root=(const float*)d_in[17];
    const float* rg1b=(const float*)d_in[18];
    const float* ln1g=(const float*)d_in[19]; const float* ln1b=(const float*)d_in[20];
    const float* rg2w=(const float*)d_in[21]; const float* rg2root=(const float*)d_in[22];
    const float* rg2b=(const float*)d_in[23];
    const float* ln2g=(const float*)d_in[24]; const float* ln2b=(const float*)d_in[25];
    const float* W2=(const float*)d_in[26]; const float* b2=(const float*)d_in[27];
    const float* W3=(const float*)d_in[28]; const float* b3=(const float*)d_in[29];
    float* out = (float*)d_out;

    // workspace layout (~79.2 MB)
    float* xa  = (float*)d_ws;                       // NN*DD
    float* xb  = xa + (size_t)NN*DD;                 // NN*DD
    float* agg = xb + (size_t)NN*DD;                 // NN*DD
    float* red = agg + (size_t)NN*DD;                // 4
    int*   deg    = (int*)(red + 4);                 // NSEG
    int*   offs   = deg + NSEG;                      // NSEG+1
    int*   cursor = offs + NSEG + 1;                 // NSEG
    int*   part   = cursor + NSEG;                   // NPART
    unsigned short* csr = (unsigned short*)(part + NPART);  // EE u16

    dim3 blk(256);
    dim3 gSq((NN+127)/128, 1);    // square GEMMs: BM=128, BN=128
    dim3 gP((NN+127)/128, 1);     // projections (BN=32)
    const int nelm_blocks = (NN*DD)/256;     // 25000, exact
    const int edge_blocks = (EE+255)/256;    // 2344
    const int gat_blocks  = (NN*64+255)/256; // 12500

    // ---- feature projections -> xa
    hipLaunchKernelGGL((gemm_k<128,32,8,2,1,false>), gP, blk, 0, stream,
                       desc, NN, 768, Wd, 32, bd, xa, DD, 0);
    hipLaunchKernelGGL((gemm_k<128,32,8,2,1,false>), gP, blk, 0, stream,
                       tweet, NN, 768, Wt, 32, bt, xa, DD, 32);
    numcat_k<<<(NN*64)/256, 256, 0, stream>>>(numf, catf, Wn, bn, Wc, bc, xa);

    // ---- CSR build (edges identical for both layers; build once)
    zero_int_k<<<(NSEG+255)/256, 256, 0, stream>>>(deg, NSEG);
    hist_k<<<edge_blocks, 256, 0, stream>>>(ei, et, deg);
    part_reduce_k<<<NPART, 256, 0, stream>>>(deg, part);
    part_scan_k<<<1, 512, 0, stream>>>(part);
    final_scan_k<<<NPART, 256, 0, stream>>>(deg, part, offs, cursor);
    place_k<<<edge_blocks, 256, 0, stream>>>(ei, et, cursor, csr);

    // ---- x = leaky(x@W1 + b1) -> xb
    hipLaunchKernelGGL((gemm_k<128,128,8,8,1,false>), gSq, blk, 0, stream,
                       xa, NN, 128, W1, 128, b1, xb, DD, 0);

    // ---- RGCN layer 1: xa = xb@root + bias + sum_r maxagg_r(xb) @ W_r
    hipLaunchKernelGGL((gemm_k<128,128,8,8,0,false>), gSq, blk, 0, stream,
                       xb, NN, 128, rg1root, 128, rg1b, xa, DD, 0);
    for (int r=0;r<2;r++) {
        gather_k<<<gat_blocks, 256, 0, stream>>>(xb, offs, csr, r, agg);
        hipLaunchKernelGGL((gemm_k<128,128,8,8,0,true>), gSq, blk, 0, stream,
                           agg, NN, 128, rg1w + (size_t)r*DD*DD, 128, nullptr, xa, DD, 0);
    }
    zero_red_k<<<1, 64, 0, stream>>>(red);
    reduce_k<<<512, 256, 0, stream>>>(xa, red);
    norm_k<<<nelm_blocks, 256, 0, stream>>>(xa, ln1g, ln1b, red);

    // ---- RGCN layer 2: xb = xa@root + bias + sum_r maxagg_r(xa) @ W_r
    hipLaunchKernelGGL((gemm_k<128,128,8,8,0,false>), gSq, blk, 0, stream,
                       xa, NN, 128, rg2root, 128, rg2b, xb, DD, 0);
    for (int r=0;r<2;r++) {
        gather_k<<<gat_blocks, 256, 0, stream>>>(xa, offs, csr, r, agg);
        hipLaunchKernelGGL((gemm_k<128,128,8,8,0,true>), gSq, blk, 0, stream,
                           agg, NN, 128, rg2w + (size_t)r*DD*DD, 128, nullptr, xb, DD, 0);
    }
    zero_red_k<<<1, 64, 0, stream>>>(red);
    reduce_k<<<512, 256, 0, stream>>>(xb, red);
    norm_k<<<nelm_blocks, 256, 0, stream>>>(xb, ln2g, ln2b, red);

    // ---- head: xa = leaky(xb@W2+b2); out = sigmoid(xa@W3 + b3)
    hipLaunchKernelGGL((gemm_k<128,128,8,8,1,false>), gSq, blk, 0, stream,
                       xb, NN, 128, W2, 128, b2, xa, DD, 0);
    head_k<<<NN, 128, 0, stream>>>(xa, W3, b3, out);
}

// Round 4
// 838.731 us; speedup vs baseline: 1.7855x; 1.4545x over previous
//
#include <hip/hip_runtime.h>
#include <cstdint>
#include <cstddef>

#define NN 50000
#define EE 600000
#define DD 128
#define NSEG (NN*2)
#define NPART ((NSEG + 255) / 256)   // 391

typedef short bf16x8 __attribute__((ext_vector_type(8)));
typedef float f32x4 __attribute__((ext_vector_type(4)));

__device__ __forceinline__ float leaky_f(float x){ return x > 0.f ? x : 0.01f*x; }

__device__ __forceinline__ unsigned short f2bf(float f){
    unsigned u = __float_as_uint(f);
    u += 0x7fffu + ((u >> 16) & 1u);       // round-to-nearest-even
    return (unsigned short)(u >> 16);
}
__device__ __forceinline__ float bf2f(unsigned short h){
    return __uint_as_float(((unsigned)h) << 16);
}

// =========== MFMA GEMM: C[M,BN cols @ c0 of 128] = act(sum_s A_s @ B_s + bias) ======
// Per block: 64 rows, 4 waves (16 rows/wave), full BN. B staged in LDS as bf16-hi,
// swizzled [ks][n] groups with 40-short stride (16B-aligned ds_read_b128, <=2-way
// bank conflicts). f32 A streams are split hi/lo in-register (2 MFMAs); bf16 A
// streams (agg) feed MFMA directly. mfma_f32_16x16x32_bf16:
//   A: a[j] = A[m=lane&15][k=(lane>>4)*8+j];  B: b[j] = B[k=(lane>>4)*8+j][n=lane&15]
//   D: d[i] = D[row=(lane>>4)*4+i][col=lane&15]
template<int K, int BN, int S, int BFMASK, int LEAKY>
__global__ __launch_bounds__(256) void mfgemm_k(
    const void* __restrict__ A0, const void* __restrict__ A1, const void* __restrict__ A2,
    int lda0,
    const float* __restrict__ B0, const float* __restrict__ B1, const float* __restrict__ B2,
    const float* __restrict__ bias, float* __restrict__ C, int c0, int M)
{
    constexpr int KCH = 128;
    constexpr int NCH = K / KCH;
    constexpr int CT = BN / 16;
    __shared__ unsigned short sB[4*BN*40];
    const int tid = threadIdx.x;
    const int lane = tid & 63;
    const int wv = tid >> 6;
    const int q = lane >> 4, n16 = lane & 15;
    const int bm = blockIdx.x * 64;
    const int arow = bm + wv*16 + n16;

    f32x4 acc[CT];
#pragma unroll
    for (int c=0;c<CT;c++) acc[c] = (f32x4){0.f,0.f,0.f,0.f};

    const void* As[3] = {A0, A1, A2};
    const float* Bs[3] = {B0, B1, B2};

#pragma unroll
    for (int s=0; s<S; s++) {
        const float* Bp = Bs[s];
        const int lda = (s==0) ? lda0 : K;
        const bool f32s = !((BFMASK >> s) & 1);
        for (int kb=0; kb<NCH; kb++) {
            __syncthreads();
            // ---- stage chunk kb of Bp (128 x BN) as bf16-hi, k-major thread map
            {
                const int n = tid % BN;
                const int kq0 = tid / BN;
                constexpr int KQSTEP = 256 / BN;
#pragma unroll
                for (int kq = kq0; kq < 32; kq += KQSTEP) {
                    int k0 = kq*4;
                    const float* gp = Bp + (size_t)(kb*KCH + k0)*BN + n;
                    float v0 = gp[0], v1 = gp[BN], v2 = gp[2*BN], v3 = gp[3*BN];
                    int ks = kq >> 3, kk = (kq & 7)*4;
                    int sa = (ks*BN + n)*40 + kk;
                    unsigned p0 = (unsigned)f2bf(v0) | ((unsigned)f2bf(v1) << 16);
                    unsigned p1 = (unsigned)f2bf(v2) | ((unsigned)f2bf(v3) << 16);
                    *reinterpret_cast<unsigned*>(&sB[sa])   = p0;
                    *reinterpret_cast<unsigned*>(&sB[sa+2]) = p1;
                }
            }
            __syncthreads();
#pragma unroll
            for (int ks=0; ks<4; ks++) {
                bf16x8 ah, al;
                if (f32s) {
                    float a[8];
                    if (arow < M) {
                        const float* ap = (const float*)As[s] + (size_t)arow*lda + kb*KCH + ks*32 + q*8;
                        float4 t0 = *reinterpret_cast<const float4*>(ap);
                        float4 t1 = *reinterpret_cast<const float4*>(ap+4);
                        a[0]=t0.x;a[1]=t0.y;a[2]=t0.z;a[3]=t0.w;
                        a[4]=t1.x;a[5]=t1.y;a[6]=t1.z;a[7]=t1.w;
                    } else {
#pragma unroll
                        for (int j=0;j<8;j++) a[j]=0.f;
                    }
#pragma unroll
                    for (int j=0;j<8;j++) {
                        unsigned short h = f2bf(a[j]);
                        ah[j] = (short)h;
                        al[j] = (short)f2bf(a[j] - bf2f(h));
                    }
                } else {
                    if (arow < M) {
                        const unsigned short* ap = (const unsigned short*)As[s]
                            + (size_t)arow*K + kb*KCH + ks*32 + q*8;
                        ah = *reinterpret_cast<const bf16x8*>(ap);
                    } else {
#pragma unroll
                        for (int j=0;j<8;j++) ah[j]=0;
                    }
                }
#pragma unroll
                for (int c=0;c<CT;c++) {
                    const unsigned short* bp = &sB[(ks*BN + c*16 + n16)*40 + q*8];
                    bf16x8 b = *reinterpret_cast<const bf16x8*>(bp);
                    acc[c] = __builtin_amdgcn_mfma_f32_16x16x32_bf16(ah, b, acc[c], 0,0,0);
                    if (f32s)
                        acc[c] = __builtin_amdgcn_mfma_f32_16x16x32_bf16(al, b, acc[c], 0,0,0);
                }
            }
        }
    }
    // ---- epilogue: bias (+leaky), store
    const int orow = bm + wv*16 + q*4;
#pragma unroll
    for (int c=0;c<CT;c++) {
        float bb = bias[c*16 + n16];
#pragma unroll
        for (int i=0;i<4;i++) {
            int r = orow + i;
            if (r < M) {
                float v = acc[c][i] + bb;
                if (LEAKY) v = leaky_f(v);
                C[(size_t)r*DD + c0 + c*16 + n16] = v;
            }
        }
    }
}

// ---------------- small-K projections (num: K=5 -> cols 64..95, cat: K=3 -> cols 96..127)
__global__ void numcat_k(const float* __restrict__ numf, const float* __restrict__ catf,
                         const float* __restrict__ Wn, const float* __restrict__ bn,
                         const float* __restrict__ Wc, const float* __restrict__ bc,
                         float* __restrict__ x)
{
    int t = blockIdx.x*blockDim.x + threadIdx.x;
    if (t >= NN*64) return;
    int n = t >> 6, c = t & 63;
    if (c < 32) {
        float acc = bn[c];
#pragma unroll
        for (int k=0;k<5;k++) acc = fmaf(numf[n*5+k], Wn[k*32+c], acc);
        x[(size_t)n*DD + 64 + c] = leaky_f(acc);
    } else {
        int cc = c - 32;
        float acc = bc[cc];
#pragma unroll
        for (int k=0;k<3;k++) acc = fmaf(catf[n*3+k], Wc[k*32+cc], acc);
        x[(size_t)n*DD + 96 + cc] = leaky_f(acc);
    }
}

// ---------------- CSR build (once per call; shared by both RGCN layers) ----------------
__global__ void zero_int_k(int* __restrict__ p, int n)
{
    int i = blockIdx.x*blockDim.x + threadIdx.x;
    if (i < n) p[i] = 0;
}

__global__ void hist_k(const int* __restrict__ ei, const int* __restrict__ et,
                       int* __restrict__ deg)
{
    int e = blockIdx.x*blockDim.x + threadIdx.x;
    if (e >= EE) return;
    atomicAdd(&deg[ei[EE + e]*2 + et[e]], 1);
}

__global__ __launch_bounds__(256) void part_reduce_k(const int* __restrict__ deg,
                                                     int* __restrict__ part)
{
    __shared__ int s[256];
    int t = threadIdx.x;
    int i = blockIdx.x*256 + t;
    s[t] = (i < NSEG) ? deg[i] : 0;
    __syncthreads();
#pragma unroll
    for (int o=128;o>0;o>>=1) {
        if (t < o) s[t] += s[t+o];
        __syncthreads();
    }
    if (t == 0) part[blockIdx.x] = s[0];
}

__global__ __launch_bounds__(512) void part_scan_k(int* __restrict__ part)
{
    __shared__ int ps[512];
    int t = threadIdx.x;
    int v = (t < NPART) ? part[t] : 0;
    ps[t] = v; __syncthreads();
    for (int o=1;o<512;o<<=1) {
        int u = (t >= o) ? ps[t-o] : 0;
        __syncthreads();
        ps[t] += u;
        __syncthreads();
    }
    if (t < NPART) part[t] = ps[t] - v;   // exclusive
}

__global__ __launch_bounds__(256) void final_scan_k(const int* __restrict__ deg,
                                                    const int* __restrict__ part,
                                                    int* __restrict__ offs,
                                                    int* __restrict__ cursor)
{
    __shared__ int ps[256];
    int t = threadIdx.x;
    int i = blockIdx.x*256 + t;
    int d = (i < NSEG) ? deg[i] : 0;
    ps[t] = d; __syncthreads();
    for (int o=1;o<256;o<<=1) {
        int u = (t >= o) ? ps[t-o] : 0;
        __syncthreads();
        ps[t] += u;
        __syncthreads();
    }
    if (i < NSEG) {
        int off = part[blockIdx.x] + ps[t] - d;
        offs[i] = off; cursor[i] = off;
    }
    if (blockIdx.x == 0 && t == 0) offs[NSEG] = EE;
}

__global__ void place_k(const int* __restrict__ ei, const int* __restrict__ et,
                        int* __restrict__ cursor, unsigned short* __restrict__ csr)
{
    int e = blockIdx.x*blockDim.x + threadIdx.x;
    if (e >= EE) return;
    int r = et[e], dst = ei[EE + e], src = ei[e];
    int pos = atomicAdd(&cursor[dst*2 + r], 1);
    csr[pos] = (unsigned short)src;    // N=50000 < 65536
}

// ---------------- max-gather per (node, rel): one wave per node, bf16 out ----------------
__global__ void gather_k(const float* __restrict__ x, const int* __restrict__ offs,
                         const unsigned short* __restrict__ csr, int r,
                         unsigned short* __restrict__ aggb)
{
    int gw = (blockIdx.x*blockDim.x + threadIdx.x) >> 6;  // global wave = node
    int lane = threadIdx.x & 63;
    if (gw >= NN) return;
    int seg = gw*2 + r;
    int beg = offs[seg], end = offs[seg+1];
    float2 m = make_float2(-3.402823466e+38f, -3.402823466e+38f);
    for (int j=beg;j<end;j++) {
        int src = csr[j];
        float2 v = *reinterpret_cast<const float2*>(x + (size_t)src*DD + lane*2);
        m.x = fmaxf(m.x, v.x);
        m.y = fmaxf(m.y, v.y);
    }
    if (beg == end) { m.x = 0.f; m.y = 0.f; }   // empty segment -> 0
    unsigned o = (unsigned)f2bf(m.x) | ((unsigned)f2bf(m.y) << 16);
    *reinterpret_cast<unsigned*>(aggb + (size_t)gw*DD + lane*2) = o;
}

// ---------------- graph layernorm ----------------
__global__ void zero_red_k(float* __restrict__ red)
{
    if (threadIdx.x < 4) red[threadIdx.x] = 0.f;
}

__global__ void reduce_k(const float* __restrict__ x, float* __restrict__ red)
{
    const int total = NN*DD;
    float s = 0.f, ss = 0.f;
    for (int i = blockIdx.x*blockDim.x + threadIdx.x; i < total; i += gridDim.x*blockDim.x) {
        float v = x[i];
        s += v; ss = fmaf(v, v, ss);
    }
#pragma unroll
    for (int o=32;o>0;o>>=1) { s += __shfl_down(s,o); ss += __shfl_down(ss,o); }
    __shared__ float bs[4], bss[4];
    int wid = threadIdx.x >> 6, lane = threadIdx.x & 63;
    if (lane == 0) { bs[wid] = s; bss[wid] = ss; }
    __syncthreads();
    if (threadIdx.x == 0) {
        atomicAdd(&red[0], bs[0]+bs[1]+bs[2]+bs[3]);
        atomicAdd(&red[1], bss[0]+bss[1]+bss[2]+bss[3]);
    }
}

__global__ void norm_k(float* __restrict__ x, const float* __restrict__ g,
                       const float* __restrict__ b, const float* __restrict__ red)
{
    const float inv = 1.f / (float)(NN*DD);
    float mu  = red[0] * inv;
    float var = red[1] * inv - mu*mu;
    float rstd = rsqrtf(var + 1e-5f);
    int i = blockIdx.x*blockDim.x + threadIdx.x;   // exactly NN*DD threads
    int c = i & 127;
    x[i] = (x[i]-mu)*rstd*g[c] + b[c];
}

// ---------------- head: out[n] = sigmoid(h . W3 + b3) ----------------
__global__ void head_k(const float* __restrict__ h, const float* __restrict__ W3,
                       const float* __restrict__ b3, float* __restrict__ out)
{
    int n = blockIdx.x;
    int t = threadIdx.x;    // 128
    float p = h[(size_t)n*DD + t] * W3[t];
#pragma unroll
    for (int o=32;o>0;o>>=1) p += __shfl_down(p,o);
    __shared__ float s2[2];
    if ((t & 63) == 0) s2[t>>6] = p;
    __syncthreads();
    if (t == 0) {
        float l = s2[0] + s2[1] + b3[0];
        out[n] = 1.f / (1.f + expf(-l));
    }
}

extern "C" void kernel_launch(void* const* d_in, const int* in_sizes, int n_in,
                              void* d_out, int out_size, void* d_ws, size_t ws_size,
                              hipStream_t stream)
{
    const float* desc  = (const float*)d_in[0];
    const float* tweet = (const float*)d_in[1];
    const float* numf  = (const float*)d_in[2];
    const float* catf  = (const float*)d_in[3];
    const int*   ei    = (const int*)d_in[4];
    const int*   et    = (const int*)d_in[5];
    const float* Wd=(const float*)d_in[6];  const float* bd=(const float*)d_in[7];
    const float* Wt=(const float*)d_in[8];  const float* bt=(const float*)d_in[9];
    const float* Wn=(const float*)d_in[10]; const float* bn=(const float*)d_in[11];
    const float* Wc=(const float*)d_in[12]; const float* bc=(const float*)d_in[13];
    const float* W1=(const float*)d_in[14]; const float* b1=(const float*)d_in[15];
    const float* rg1w=(const float*)d_in[16]; const float* rg1root=(const float*)d_in[17];
    const float* rg1b=(const float*)d_in[18];
    const float* ln1g=(const float*)d_in[19]; const float* ln1b=(const float*)d_in[20];
    const float* rg2w=(const float*)d_in[21]; const float* rg2root=(const float*)d_in[22];
    const float* rg2b=(const float*)d_in[23];
    const float* ln2g=(const float*)d_in[24]; const float* ln2b=(const float*)d_in[25];
    const float* W2=(const float*)d_in[26]; const float* b2=(const float*)d_in[27];
    const float* W3=(const float*)d_in[28]; const float* b3=(const float*)d_in[29];
    float* out = (float*)d_out;

    // workspace layout (~81 MB)
    float* xa  = (float*)d_ws;                             // NN*DD f32
    float* xb  = xa + (size_t)NN*DD;                       // NN*DD f32
    unsigned short* aggb = (unsigned short*)(xb + (size_t)NN*DD);  // 2 * NN*DD bf16
    unsigned short* aggb0 = aggb;
    unsigned short* aggb1 = aggb + (size_t)NN*DD;
    float* red = (float*)(aggb + (size_t)2*NN*DD);         // 4
    int*   deg    = (int*)(red + 4);                       // NSEG
    int*   offs   = deg + NSEG;                            // NSEG+1
    int*   cursor = offs + NSEG + 1;                       // NSEG
    int*   part   = cursor + NSEG;                         // NPART
    unsigned short* csr = (unsigned short*)(part + NPART); // EE u16

    dim3 blk(256);
    const int mblocks = (NN + 63) / 64;      // 782
    const int nelm_blocks = (NN*DD)/256;     // 25000, exact
    const int edge_blocks = (EE+255)/256;    // 2344
    const int gat_blocks  = (NN*64+255)/256; // 12500

    // ---- feature projections -> xa (cols 0..63), numcat -> cols 64..127
    hipLaunchKernelGGL((mfgemm_k<768,32,1,0,1>), dim3(mblocks), blk, 0, stream,
                       desc, nullptr, nullptr, 768, Wd, nullptr, nullptr, bd, xa, 0, NN);
    hipLaunchKernelGGL((mfgemm_k<768,32,1,0,1>), dim3(mblocks), blk, 0, stream,
                       tweet, nullptr, nullptr, 768, Wt, nullptr, nullptr, bt, xa, 32, NN);
    numcat_k<<<(NN*64)/256, 256, 0, stream>>>(numf, catf, Wn, bn, Wc, bc, xa);

    // ---- CSR build (edges identical for both layers; build once)
    zero_int_k<<<(NSEG+255)/256, 256, 0, stream>>>(deg, NSEG);
    hist_k<<<edge_blocks, 256, 0, stream>>>(ei, et, deg);
    part_reduce_k<<<NPART, 256, 0, stream>>>(deg, part);
    part_scan_k<<<1, 512, 0, stream>>>(part);
    final_scan_k<<<NPART, 256, 0, stream>>>(deg, part, offs, cursor);
    place_k<<<edge_blocks, 256, 0, stream>>>(ei, et, cursor, csr);

    // ---- x = leaky(x@W1 + b1) -> xb
    hipLaunchKernelGGL((mfgemm_k<128,128,1,0,1>), dim3(mblocks), blk, 0, stream,
                       xa, nullptr, nullptr, 128, W1, nullptr, nullptr, b1, xb, 0, NN);

    // ---- RGCN layer 1 (fused): xa = xb@root + agg0@W0 + agg1@W1 + bias
    gather_k<<<gat_blocks, 256, 0, stream>>>(xb, offs, csr, 0, aggb0);
    gather_k<<<gat_blocks, 256, 0, stream>>>(xb, offs, csr, 1, aggb1);
    hipLaunchKernelGGL((mfgemm_k<128,128,3,6,0>), dim3(mblocks), blk, 0, stream,
                       xb, aggb0, aggb1, 128,
                       rg1root, rg1w, rg1w + (size_t)DD*DD, rg1b, xa, 0, NN);
    zero_red_k<<<1, 64, 0, stream>>>(red);
    reduce_k<<<512, 256, 0, stream>>>(xa, red);
    norm_k<<<nelm_blocks, 256, 0, stream>>>(xa, ln1g, ln1b, red);

    // ---- RGCN layer 2 (fused): xb = xa@root + agg0@W0 + agg1@W1 + bias
    gather_k<<<gat_blocks, 256, 0, stream>>>(xa, offs, csr, 0, aggb0);
    gather_k<<<gat_blocks, 256, 0, stream>>>(xa, offs, csr, 1, aggb1);
    hipLaunchKernelGGL((mfgemm_k<128,128,3,6,0>), dim3(mblocks), blk, 0, stream,
                       xa, aggb0, aggb1, 128,
                       rg2root, rg2w, rg2w + (size_t)DD*DD, rg2b, xb, 0, NN);
    zero_red_k<<<1, 64, 0, stream>>>(red);
    reduce_k<<<512, 256, 0, stream>>>(xb, red);
    norm_k<<<nelm_blocks, 256, 0, stream>>>(xb, ln2g, ln2b, red);

    // ---- head: xa = leaky(xb@W2+b2); out = sigmoid(xa@W3 + b3)
    hipLaunchKernelGGL((mfgemm_k<128,128,1,0,1>), dim3(mblocks), blk, 0, stream,
                       xb, nullptr, nullptr, 128, W2, nullptr, nullptr, b2, xa, 0, NN);
    head_k<<<NN, 128, 0, stream>>>(xa, W3, b3, out);
}

// Round 5
// 822.525 us; speedup vs baseline: 1.8207x; 1.0197x over previous
//
#include <hip/hip_runtime.h>
#include <cstdint>
#include <cstddef>

#define NN 50000
#define EE 600000
#define DD 128
#define NSEG (NN*2)
#define NPART ((NSEG + 255) / 256)   // 391

typedef short bf16x8 __attribute__((ext_vector_type(8)));
typedef float f32x4 __attribute__((ext_vector_type(4)));

__device__ __forceinline__ float leaky_f(float x){ return x > 0.f ? x : 0.01f*x; }

__device__ __forceinline__ unsigned short f2bf(float f){
    unsigned u = __float_as_uint(f);
    u += 0x7fffu + ((u >> 16) & 1u);       // round-to-nearest-even
    return (unsigned short)(u >> 16);
}

// truncation hi/lo split: hi=trunc_bf16(a), lo=trunc_bf16(a-hi). err <= 2^-17 |a|
__device__ __forceinline__ void split8(const float* a, bf16x8& hi, bf16x8& lo){
#pragma unroll
    for (int j=0;j<8;j++){
        unsigned u  = __float_as_uint(a[j]);
        unsigned uh = u & 0xFFFF0000u;
        hi[j] = (short)(uh >> 16);
        float lf = a[j] - __uint_as_float(uh);
        lo[j] = (short)(__float_as_uint(lf) >> 16);
    }
}

// ============ dual projection kernel: K=768, BN=32, grid.y selects desc/tweet ========
// per block: 64 rows x 32 cols. mfma_f32_16x16x32_bf16, A split hi/lo (truncation).
__global__ __launch_bounds__(256) void proj_k(
    const float* __restrict__ A0, const float* __restrict__ A1,
    const float* __restrict__ B0, const float* __restrict__ B1,
    const float* __restrict__ bias0, const float* __restrict__ bias1,
    float* __restrict__ C, int M)
{
    constexpr int K = 768, BN = 32, CT = 2;
    __shared__ unsigned short sB[4*BN*40];
    const int tid = threadIdx.x;
    const int lane = tid & 63;
    const int wv = tid >> 6;
    const int q = lane >> 4, n16 = lane & 15;
    const int bm = blockIdx.x * 64;
    const int arow = bm + wv*16 + n16;
    const float* A = blockIdx.y ? A1 : A0;
    const float* B = blockIdx.y ? B1 : B0;
    const float* bias = blockIdx.y ? bias1 : bias0;
    const int c0 = blockIdx.y * 32;

    f32x4 acc[CT];
#pragma unroll
    for (int c=0;c<CT;c++) acc[c] = (f32x4){0.f,0.f,0.f,0.f};

    for (int kb=0; kb<K/128; kb++) {
        __syncthreads();
        {   // stage B chunk (128 x 32) as bf16 RNE
            const int n = tid % BN;
            const int kq0 = tid / BN;          // 0..7
#pragma unroll
            for (int kq = kq0; kq < 32; kq += 8) {
                const float* gp = B + (size_t)(kb*128 + kq*4)*BN + n;
                float v0 = gp[0], v1 = gp[BN], v2 = gp[2*BN], v3 = gp[3*BN];
                int ks = kq >> 3, kk = (kq & 7)*4;
                int sa = (ks*BN + n)*40 + kk;
                *reinterpret_cast<unsigned*>(&sB[sa])   = (unsigned)f2bf(v0) | ((unsigned)f2bf(v1) << 16);
                *reinterpret_cast<unsigned*>(&sB[sa+2]) = (unsigned)f2bf(v2) | ((unsigned)f2bf(v3) << 16);
            }
        }
        __syncthreads();
#pragma unroll
        for (int ks=0; ks<4; ks++) {
            float a[8];
            if (arow < M) {
                const float* ap = A + (size_t)arow*K + kb*128 + ks*32 + q*8;
                float4 t0 = *reinterpret_cast<const float4*>(ap);
                float4 t1 = *reinterpret_cast<const float4*>(ap+4);
                a[0]=t0.x;a[1]=t0.y;a[2]=t0.z;a[3]=t0.w;
                a[4]=t1.x;a[5]=t1.y;a[6]=t1.z;a[7]=t1.w;
            } else {
#pragma unroll
                for (int j=0;j<8;j++) a[j]=0.f;
            }
            bf16x8 ah, al;
            split8(a, ah, al);
#pragma unroll
            for (int c=0;c<CT;c++) {
                bf16x8 b = *reinterpret_cast<const bf16x8*>(&sB[(ks*BN + c*16 + n16)*40 + q*8]);
                acc[c] = __builtin_amdgcn_mfma_f32_16x16x32_bf16(ah, b, acc[c], 0,0,0);
                acc[c] = __builtin_amdgcn_mfma_f32_16x16x32_bf16(al, b, acc[c], 0,0,0);
            }
        }
    }
    const int orow = bm + wv*16 + q*4;
#pragma unroll
    for (int c=0;c<CT;c++) {
        float bb = bias[c*16 + n16];
#pragma unroll
        for (int i=0;i<4;i++) {
            int r = orow + i;
            if (r < M) C[(size_t)r*DD + c0 + c*16 + n16] = leaky_f(acc[c][i] + bb);
        }
    }
}

// ============ K=128 MFMA GEMM, BN=128, multi-stage accumulate + fused epilogues ======
// S stages: C = sum_s A_s @ B_s (+bias). BFMASK bit s => A_s is bf16 (else f32,
// split hi/lo). LEAKY: apply leaky. HEAD: no C store; out[n]=sigmoid(h.W3+b3).
// LNRED: atomically accumulate sum/sumsq of stored C into red[0..1].
template<int S,int BFMASK,int LEAKY,int HEAD,int LNRED>
__global__ __launch_bounds__(256) void mfgemm_k(
    const void* __restrict__ A0, const void* __restrict__ A1, const void* __restrict__ A2,
    const float* __restrict__ B0, const float* __restrict__ B1, const float* __restrict__ B2,
    const float* __restrict__ bias, float* __restrict__ C, int M,
    const float* __restrict__ W3, const float* __restrict__ b3,
    float* __restrict__ red, float* __restrict__ outv)
{
    constexpr int BN = 128, CT = 8;
    __shared__ unsigned short sB[4*BN*40];
    const int tid = threadIdx.x;
    const int lane = tid & 63;
    const int wv = tid >> 6;
    const int q = lane >> 4, n16 = lane & 15;
    const int bm = blockIdx.x * 64;
    const int arow = bm + wv*16 + n16;

    f32x4 acc[CT];
#pragma unroll
    for (int c=0;c<CT;c++) acc[c] = (f32x4){0.f,0.f,0.f,0.f};

    const void* As[3] = {A0, A1, A2};
    const float* Bs[3] = {B0, B1, B2};

#pragma unroll
    for (int s=0; s<S; s++) {
        const bool f32s = !((BFMASK >> s) & 1);
        __syncthreads();
        {   // stage B_s (128x128) as bf16 RNE
            const float* Bp = Bs[s];
            const int n = tid % BN;
            const int kq0 = tid / BN;          // 0..1
#pragma unroll
            for (int kq = kq0; kq < 32; kq += 2) {
                const float* gp = Bp + (size_t)(kq*4)*BN + n;
                float v0 = gp[0], v1 = gp[BN], v2 = gp[2*BN], v3 = gp[3*BN];
                int ks = kq >> 3, kk = (kq & 7)*4;
                int sa = (ks*BN + n)*40 + kk;
                *reinterpret_cast<unsigned*>(&sB[sa])   = (unsigned)f2bf(v0) | ((unsigned)f2bf(v1) << 16);
                *reinterpret_cast<unsigned*>(&sB[sa+2]) = (unsigned)f2bf(v2) | ((unsigned)f2bf(v3) << 16);
            }
        }
        __syncthreads();
#pragma unroll
        for (int ks=0; ks<4; ks++) {
            bf16x8 ah, al;
            if (f32s) {
                float a[8];
                if (arow < M) {
                    const float* ap = (const float*)As[s] + (size_t)arow*DD + ks*32 + q*8;
                    float4 t0 = *reinterpret_cast<const float4*>(ap);
                    float4 t1 = *reinterpret_cast<const float4*>(ap+4);
                    a[0]=t0.x;a[1]=t0.y;a[2]=t0.z;a[3]=t0.w;
                    a[4]=t1.x;a[5]=t1.y;a[6]=t1.z;a[7]=t1.w;
                } else {
#pragma unroll
                    for (int j=0;j<8;j++) a[j]=0.f;
                }
                split8(a, ah, al);
            } else {
                if (arow < M) {
                    const unsigned short* ap = (const unsigned short*)As[s]
                        + (size_t)arow*DD + ks*32 + q*8;
                    ah = *reinterpret_cast<const bf16x8*>(ap);
                } else {
#pragma unroll
                    for (int j=0;j<8;j++) ah[j]=0;
                }
            }
#pragma unroll
            for (int c=0;c<CT;c++) {
                bf16x8 b = *reinterpret_cast<const bf16x8*>(&sB[(ks*BN + c*16 + n16)*40 + q*8]);
                acc[c] = __builtin_amdgcn_mfma_f32_16x16x32_bf16(ah, b, acc[c], 0,0,0);
                if (f32s)
                    acc[c] = __builtin_amdgcn_mfma_f32_16x16x32_bf16(al, b, acc[c], 0,0,0);
            }
        }
    }

    // ---- epilogue
    const int orow = bm + wv*16 + q*4;
    if (HEAD) {
        float w3c[CT];
#pragma unroll
        for (int c=0;c<CT;c++) w3c[c] = W3[c*16 + n16];
        float bb3 = b3[0];
#pragma unroll
        for (int i=0;i<4;i++) {
            float t = 0.f;
#pragma unroll
            for (int c=0;c<CT;c++) {
                float v = acc[c][i] + bias[c*16 + n16];
                if (LEAKY) v = leaky_f(v);
                t = fmaf(v, w3c[c], t);
            }
#pragma unroll
            for (int m=1;m<16;m<<=1) t += __shfl_xor(t, m);
            int r = orow + i;
            if (n16 == 0 && r < M) outv[r] = 1.f / (1.f + expf(-(t + bb3)));
        }
    } else {
        float s = 0.f, ss = 0.f;
#pragma unroll
        for (int c=0;c<CT;c++) {
            float bb = bias[c*16 + n16];
#pragma unroll
            for (int i=0;i<4;i++) {
                int r = orow + i;
                if (r < M) {
                    float v = acc[c][i] + bb;
                    if (LEAKY) v = leaky_f(v);
                    C[(size_t)r*DD + c*16 + n16] = v;
                    if (LNRED) { s += v; ss = fmaf(v, v, ss); }
                }
            }
        }
        if (LNRED) {
#pragma unroll
            for (int o=32;o>0;o>>=1) { s += __shfl_down(s,o); ss += __shfl_down(ss,o); }
            __shared__ float rs[4], rss[4];
            if (lane == 0) { rs[wv] = s; rss[wv] = ss; }
            __syncthreads();
            if (tid == 0) {
                atomicAdd(&red[0], rs[0]+rs[1]+rs[2]+rs[3]);
                atomicAdd(&red[1], rss[0]+rss[1]+rss[2]+rss[3]);
            }
        }
    }
}

// ---------------- small-K projections (num: cols 64..95, cat: cols 96..127) --------
__global__ void numcat_k(const float* __restrict__ numf, const float* __restrict__ catf,
                         const float* __restrict__ Wn, const float* __restrict__ bn,
                         const float* __restrict__ Wc, const float* __restrict__ bc,
                         float* __restrict__ x)
{
    int t = blockIdx.x*blockDim.x + threadIdx.x;
    if (t >= NN*64) return;
    int n = t >> 6, c = t & 63;
    if (c < 32) {
        float acc = bn[c];
#pragma unroll
        for (int k=0;k<5;k++) acc = fmaf(numf[n*5+k], Wn[k*32+c], acc);
        x[(size_t)n*DD + 64 + c] = leaky_f(acc);
    } else {
        int cc = c - 32;
        float acc = bc[cc];
#pragma unroll
        for (int k=0;k<3;k++) acc = fmaf(catf[n*3+k], Wc[k*32+cc], acc);
        x[(size_t)n*DD + 96 + cc] = leaky_f(acc);
    }
}

// ---------------- CSR build ----------------
__global__ void zero_int_k(int* __restrict__ p, int n)
{
    int i = blockIdx.x*blockDim.x + threadIdx.x;
    if (i < n) p[i] = 0;
}

__global__ void hist_k(const int* __restrict__ ei, const int* __restrict__ et,
                       int* __restrict__ deg)
{
    int e = blockIdx.x*blockDim.x + threadIdx.x;
    if (e >= EE) return;
    atomicAdd(&deg[ei[EE + e]*2 + et[e]], 1);
}

__global__ __launch_bounds__(256) void part_reduce_k(const int* __restrict__ deg,
                                                     int* __restrict__ part)
{
    __shared__ int s[256];
    int t = threadIdx.x;
    int i = blockIdx.x*256 + t;
    s[t] = (i < NSEG) ? deg[i] : 0;
    __syncthreads();
#pragma unroll
    for (int o=128;o>0;o>>=1) {
        if (t < o) s[t] += s[t+o];
        __syncthreads();
    }
    if (t == 0) part[blockIdx.x] = s[0];
}

__global__ __launch_bounds__(512) void part_scan_k(int* __restrict__ part)
{
    __shared__ int ps[512];
    int t = threadIdx.x;
    int v = (t < NPART) ? part[t] : 0;
    ps[t] = v; __syncthreads();
    for (int o=1;o<512;o<<=1) {
        int u = (t >= o) ? ps[t-o] : 0;
        __syncthreads();
        ps[t] += u;
        __syncthreads();
    }
    if (t < NPART) part[t] = ps[t] - v;   // exclusive
}

__global__ __launch_bounds__(256) void final_scan_k(const int* __restrict__ deg,
                                                    const int* __restrict__ part,
                                                    int* __restrict__ offs,
                                                    int* __restrict__ cursor)
{
    __shared__ int ps[256];
    int t = threadIdx.x;
    int i = blockIdx.x*256 + t;
    int d = (i < NSEG) ? deg[i] : 0;
    ps[t] = d; __syncthreads();
    for (int o=1;o<256;o<<=1) {
        int u = (t >= o) ? ps[t-o] : 0;
        __syncthreads();
        ps[t] += u;
        __syncthreads();
    }
    if (i < NSEG) {
        int off = part[blockIdx.x] + ps[t] - d;
        offs[i] = off; cursor[i] = off;
    }
    if (blockIdx.x == 0 && t == 0) offs[NSEG] = EE;
}

__global__ void place_k(const int* __restrict__ ei, const int* __restrict__ et,
                        int* __restrict__ cursor, unsigned short* __restrict__ csr)
{
    int e = blockIdx.x*blockDim.x + threadIdx.x;
    if (e >= EE) return;
    int r = et[e], dst = ei[EE + e], src = ei[e];
    int pos = atomicAdd(&cursor[dst*2 + r], 1);
    csr[pos] = (unsigned short)src;    // N=50000 < 65536
}

// ---------------- merged max-gather: one wave per (node,rel) segment ----------------
// also zeroes red[0..3] (block 0) for the following LN-reduce.
__global__ void gather2_k(const float* __restrict__ x, const int* __restrict__ offs,
                          const unsigned short* __restrict__ csr,
                          unsigned short* __restrict__ aggb, float* __restrict__ red)
{
    if (blockIdx.x == 0 && threadIdx.x < 4) red[threadIdx.x] = 0.f;
    int seg = (blockIdx.x*blockDim.x + threadIdx.x) >> 6;   // segment = node*2+r
    int lane = threadIdx.x & 63;
    if (seg >= NSEG) return;
    int node = seg >> 1, r = seg & 1;
    int beg = offs[seg], end = offs[seg+1];
    float2 m = make_float2(-3.402823466e+38f, -3.402823466e+38f);
    for (int j=beg;j<end;j++) {
        int src = csr[j];
        float2 v = *reinterpret_cast<const float2*>(x + (size_t)src*DD + lane*2);
        m.x = fmaxf(m.x, v.x);
        m.y = fmaxf(m.y, v.y);
    }
    if (beg == end) { m.x = 0.f; m.y = 0.f; }
    unsigned o = (unsigned)f2bf(m.x) | ((unsigned)f2bf(m.y) << 16);
    *reinterpret_cast<unsigned*>(aggb + (size_t)r*NN*DD + (size_t)node*DD + lane*2) = o;
}

// ---------------- graph layernorm apply ----------------
__global__ void norm_k(float* __restrict__ x, const float* __restrict__ g,
                       const float* __restrict__ b, const float* __restrict__ red)
{
    const float inv = 1.f / (float)(NN*DD);
    float mu  = red[0] * inv;
    float var = red[1] * inv - mu*mu;
    float rstd = rsqrtf(var + 1e-5f);
    int i = blockIdx.x*blockDim.x + threadIdx.x;   // exactly NN*DD threads
    int c = i & 127;
    x[i] = (x[i]-mu)*rstd*g[c] + b[c];
}

extern "C" void kernel_launch(void* const* d_in, const int* in_sizes, int n_in,
                              void* d_out, int out_size, void* d_ws, size_t ws_size,
                              hipStream_t stream)
{
    const float* desc  = (const float*)d_in[0];
    const float* tweet = (const float*)d_in[1];
    const float* numf  = (const float*)d_in[2];
    const float* catf  = (const float*)d_in[3];
    const int*   ei    = (const int*)d_in[4];
    const int*   et    = (const int*)d_in[5];
    const float* Wd=(const float*)d_in[6];  const float* bd=(const float*)d_in[7];
    const float* Wt=(const float*)d_in[8];  const float* bt=(const float*)d_in[9];
    const float* Wn=(const float*)d_in[10]; const float* bn=(const float*)d_in[11];
    const float* Wc=(const float*)d_in[12]; const float* bc=(const float*)d_in[13];
    const float* W1=(const float*)d_in[14]; const float* b1=(const float*)d_in[15];
    const float* rg1w=(const float*)d_in[16]; const float* rg1root=(const float*)d_in[17];
    const float* rg1b=(const float*)d_in[18];
    const float* ln1g=(const float*)d_in[19]; const float* ln1b=(const float*)d_in[20];
    const float* rg2w=(const float*)d_in[21]; const float* rg2root=(const float*)d_in[22];
    const float* rg2b=(const float*)d_in[23];
    const float* ln2g=(const float*)d_in[24]; const float* ln2b=(const float*)d_in[25];
    const float* W2=(const float*)d_in[26]; const float* b2=(const float*)d_in[27];
    const float* W3=(const float*)d_in[28]; const float* b3=(const float*)d_in[29];
    float* out = (float*)d_out;

    // workspace layout (~81 MB)
    float* xa  = (float*)d_ws;                             // NN*DD f32
    float* xb  = xa + (size_t)NN*DD;                       // NN*DD f32
    unsigned short* aggb = (unsigned short*)(xb + (size_t)NN*DD);  // 2*NN*DD bf16
    unsigned short* aggb0 = aggb;
    unsigned short* aggb1 = aggb + (size_t)NN*DD;
    float* red = (float*)(aggb + (size_t)2*NN*DD);         // 4
    int*   deg    = (int*)(red + 4);                       // NSEG
    int*   offs   = deg + NSEG;                            // NSEG+1
    int*   cursor = offs + NSEG + 1;                       // NSEG
    int*   part   = cursor + NSEG;                         // NPART
    unsigned short* csr = (unsigned short*)(part + NPART); // EE u16

    dim3 blk(256);
    const int mblocks = (NN + 63) / 64;        // 782
    const int nelm_blocks = (NN*DD)/256;       // 25000
    const int edge_blocks = (EE+255)/256;      // 2344
    const int seg_blocks  = (NSEG*64)/256;     // 25000

    // 1. dual projection -> xa cols 0..63 ; 2. numcat -> cols 64..127
    proj_k<<<dim3(mblocks,2), blk, 0, stream>>>(desc, tweet, Wd, Wt, bd, bt, xa, NN);
    numcat_k<<<(NN*64)/256, 256, 0, stream>>>(numf, catf, Wn, bn, Wc, bc, xa);

    // 3-8. CSR build (edges identical for both layers)
    zero_int_k<<<(NSEG+255)/256, 256, 0, stream>>>(deg, NSEG);
    hist_k<<<edge_blocks, 256, 0, stream>>>(ei, et, deg);
    part_reduce_k<<<NPART, 256, 0, stream>>>(deg, part);
    part_scan_k<<<1, 512, 0, stream>>>(part);
    final_scan_k<<<NPART, 256, 0, stream>>>(deg, part, offs, cursor);
    place_k<<<edge_blocks, 256, 0, stream>>>(ei, et, cursor, csr);

    // 9. xb = leaky(xa@W1 + b1)
    hipLaunchKernelGGL((mfgemm_k<1,0,1,0,0>), dim3(mblocks), blk, 0, stream,
                       xa, nullptr, nullptr, W1, nullptr, nullptr, b1, xb, NN,
                       nullptr, nullptr, nullptr, nullptr);

    // 10-12. RGCN layer 1 (fused) + LN1
    gather2_k<<<seg_blocks, 256, 0, stream>>>(xb, offs, csr, aggb, red);
    hipLaunchKernelGGL((mfgemm_k<3,6,0,0,1>), dim3(mblocks), blk, 0, stream,
                       xb, aggb0, aggb1,
                       rg1root, rg1w, rg1w + (size_t)DD*DD, rg1b, xa, NN,
                       nullptr, nullptr, red, nullptr);
    norm_k<<<nelm_blocks, 256, 0, stream>>>(xa, ln1g, ln1b, red);

    // 13-15. RGCN layer 2 (fused) + LN2
    gather2_k<<<seg_blocks, 256, 0, stream>>>(xa, offs, csr, aggb, red);
    hipLaunchKernelGGL((mfgemm_k<3,6,0,0,1>), dim3(mblocks), blk, 0, stream,
                       xa, aggb0, aggb1,
                       rg2root, rg2w, rg2w + (size_t)DD*DD, rg2b, xb, NN,
                       nullptr, nullptr, red, nullptr);
    norm_k<<<nelm_blocks, 256, 0, stream>>>(xb, ln2g, ln2b, red);

    // 16. head fused into W2 GEMM epilogue: out = sigmoid(leaky(xb@W2+b2)@W3 + b3)
    hipLaunchKernelGGL((mfgemm_k<1,0,1,1,0>), dim3(mblocks), blk, 0, stream,
                       xb, nullptr, nullptr, W2, nullptr, nullptr, b2, nullptr, NN,
                       W3, b3, nullptr, out);
}